// Round 4
// baseline (274.395 us; speedup 1.0000x reference)
//
#include <hip/hip_runtime.h>

#define OUTD 7
#define PD 14             // 14 sample coords per axis
#define NCH 256
#define CHUNK 8           // channels per block -> grid (N, 32)
#define NELEM (CHUNK * 49)   // 392 outputs per block
#define CAP 1200          // floats per channel window (ww4*wh <= CAP; worst-case ~1142)

// ---------------- prepass: sort ROIs by (level, img, morton) ----------------
__global__ __launch_bounds__(1024)
void sort_kernel(const float* __restrict__ boxes,
                 const int*   __restrict__ img_ids,
                 int* __restrict__ order, int N)
{
    __shared__ unsigned long long kv[1024];
    const int t = threadIdx.x;

    unsigned int key = 0xFFFFFFFFu;
    if (t < N) {
        const float bx1 = boxes[t * 4 + 0];
        const float by1 = boxes[t * 4 + 1];
        const float bx2 = boxes[t * 4 + 2];
        const float by2 = boxes[t * 4 + 3];
        const float area = (bx2 - bx1) * (by2 - by1);
        const float s = sqrtf(area);
        float lvlf = floorf(4.0f + log2f(s / 224.0f + 1e-6f));
        lvlf = fminf(fmaxf(lvlf, 2.0f), 5.0f);
        const int lvl = (int)lvlf - 2;
        const float scales[4] = {0.25f, 0.125f, 0.0625f, 0.03125f};
        const float sc = scales[lvl];
        int cx = (int)(0.5f * (bx1 + bx2) * sc);
        int cy = (int)(0.5f * (by1 + by2) * sc);
        cx = min(max(cx, 0), 127);
        cy = min(max(cy, 0), 127);
        unsigned int m = 0;
#pragma unroll
        for (int b = 0; b < 7; ++b)
            m |= ((cy >> b) & 1u) << (2 * b + 1) | ((cx >> b) & 1u) << (2 * b);
        key = ((((unsigned)lvl << 1) | (unsigned)img_ids[t]) << 14) | m;
    }
    kv[t] = ((unsigned long long)key << 32) | (unsigned)t;
    __syncthreads();

    for (int k = 2; k <= 1024; k <<= 1) {
        for (int j = k >> 1; j > 0; j >>= 1) {
            const int ixj = t ^ j;
            if (ixj > t) {
                const bool up = ((t & k) == 0);
                const unsigned long long a = kv[t], b = kv[ixj];
                if ((a > b) == up) { kv[t] = b; kv[ixj] = a; }
            }
            __syncthreads();
        }
    }
    if (t < N) order[t] = (int)(kv[t] & 0xFFFFFFFFu);
}

// ---------------- main pooler: LDS window staging ----------------
// Model (round-3 evidence): scattered VMEM costs ~1 cycle per LANE per CU in
// TA/L1, independent of occupancy (27%->73% occupancy: no change). Fix:
// stage the ROI's feature window into LDS with coalesced dwordx4 loads
// (FPN level mapping bounds window area <= ~1150 floats), gather from LDS.
__global__ __launch_bounds__(256)
void pooler_kernel(const float* __restrict__ f0,
                   const float* __restrict__ f1,
                   const float* __restrict__ f2,
                   const float* __restrict__ f3,
                   const float* __restrict__ boxes,
                   const int*   __restrict__ img_ids,
                   const int*   __restrict__ order,
                   float* __restrict__ out, int N)
{
    int bx = blockIdx.x;
    int sidx;
    if ((N & 7) == 0) {
        sidx = (bx & 7) * (N >> 3) + (bx >> 3);   // XCD-contiguous runs
    } else {
        sidx = bx;
    }
    const int roi = order[sidx];

    const int c0  = blockIdx.y * CHUNK;
    const int t   = threadIdx.x;

    const float bx1 = boxes[roi * 4 + 0];
    const float by1 = boxes[roi * 4 + 1];
    const float bx2 = boxes[roi * 4 + 2];
    const float by2 = boxes[roi * 4 + 3];

    const float area = (bx2 - bx1) * (by2 - by1);
    const float s    = sqrtf(area);
    float lvlf = floorf(4.0f + log2f(s / 224.0f + 1e-6f));
    lvlf = fminf(fmaxf(lvlf, 2.0f), 5.0f);
    const int lvl = (int)lvlf - 2;   // 0..3

    const float scales[4] = {0.25f, 0.125f, 0.0625f, 0.03125f};
    const int   dims[4]   = {200, 100, 50, 25};
    const float* feats[4] = {f0, f1, f2, f3};

    const float scale = scales[lvl];
    const int H = dims[lvl];
    const int W = H;
    const int plane = H * W;

    const int img = img_ids[roi];
    const float* __restrict__ base0 =
        feats[lvl] + (size_t)img * NCH * (size_t)plane + (size_t)c0 * plane;

    const float x1 = bx1 * scale, y1 = by1 * scale;
    const float x2 = bx2 * scale, y2 = by2 * scale;
    const float roi_w = fmaxf(x2 - x1, 1.0f);
    const float roi_h = fmaxf(y2 - y1, 1.0f);
    const float bw = roi_w / (float)OUTD;
    const float bh = roi_h / (float)OUTD;

    __shared__ float  s_win[CHUNK * CAP + 8];   // +8 slack for read2 offset1 over-read
    __shared__ float4 s_ytab[PD];
    __shared__ float4 s_xtab[PD];

    // ---- window bounds (uniform across block; ulp-guarded superset) ----
    const float xs_min = x1 + 0.25f * bw;
    const float xs_max = x1 + 6.75f * bw;
    const float ys_min = y1 + 0.25f * bh;
    const float ys_max = y1 + 6.75f * bh;
    const float gx = (fabsf(xs_min) + fabsf(xs_max)) * 4e-7f + 2e-6f;
    const float gy = (fabsf(ys_min) + fabsf(ys_max)) * 4e-7f + 2e-6f;
    const float xminc = fminf(fmaxf(xs_min - gx, 0.0f), (float)(W - 1));
    const float xmaxc = fminf(fmaxf(xs_max + gx, 0.0f), (float)(W - 1));
    const float yminc = fminf(fmaxf(ys_min - gy, 0.0f), (float)(H - 1));
    const float ymaxc = fminf(fmaxf(ys_max + gy, 0.0f), (float)(H - 1));
    const int cl  = (int)floorf(xminc);
    const int chi = min((int)floorf(xmaxc) + 1, W - 1);
    const int ylo = (int)floorf(yminc);
    const int yhi = min((int)floorf(ymaxc) + 1, H - 1);
    const int cl4  = cl & ~3;                    // 16B-align window start
    const int wseg = (chi - cl4 + 4) >> 2;       // 4-float segments per row
    const int ww4  = wseg << 2;                  // LDS row stride (floats)
    const int wh   = yhi - ylo + 1;
    const bool staged = (ww4 * wh) <= CAP;       // geometry guarantees true; fallback kept

    float* __restrict__ outbase = out + ((size_t)roi * NCH + c0) * 49;

    if (staged) {
        // ---- tap tables (window-relative; row offsets pre-multiplied) ----
        if (t < PD) {
            const int i = t >> 1, j = t & 1;
            const float yg = y1 + (float)i * bh + ((float)j + 0.5f) * bh * 0.5f;
            const float v = ((yg >= -1.0f) && (yg <= (float)H)) ? 1.0f : 0.0f;
            const float y = fminf(fmaxf(yg, 0.0f), (float)(H - 1));
            const int y0 = (int)floorf(y);
            const float ly = y - (float)y0;
            const int r0 = y0 - ylo;                        // >=0 by guard
            const int r1 = min(y0 + 1, yhi) - ylo;          // clamp: ly==0 at bottom edge
            float4 r;
            r.x = __int_as_float(r0 * ww4);
            r.y = __int_as_float(r1 * ww4);
            r.z = (1.0f - ly) * v;
            r.w = ly * v;
            s_ytab[t] = r;
        } else if (t < 2 * PD) {
            const int tt = t - PD;
            const int i = tt >> 1, j = tt & 1;
            const float xg = x1 + (float)i * bw + ((float)j + 0.5f) * bw * 0.5f;
            const float v = ((xg >= -1.0f) && (xg <= (float)W)) ? 1.0f : 0.0f;
            const float x = fminf(fmaxf(xg, 0.0f), (float)(W - 1));
            const int x0 = (int)floorf(x);
            const float lx = x - (float)x0;
            float4 r;
            r.x = __int_as_float(x0 - cl4);                 // tap pair (dx, dx+1); lx==0 at right edge
            r.y = (1.0f - lx) * v;
            r.z = lx * v;
            r.w = 0.0f;
            s_xtab[tt] = r;
        }

        // ---- stage window: coalesced dwordx4 row segments, 8 channels batched ----
        const int S = wh * wseg;   // segments per channel
        for (int r = t; r < S; r += 256) {
            const int row  = r / wseg;
            const int col  = (r - row * wseg) << 2;
            const int rowo = (ylo + row) * W;
            const int loff = row * ww4 + col;
            float4 v[CHUNK];
            if (cl4 + col + 3 < W) {
                const int goff = rowo + cl4 + col;
#pragma unroll
                for (int ch = 0; ch < CHUNK; ++ch)
                    v[ch] = *(const float4*)(base0 + (size_t)ch * plane + goff);
            } else {
                // tail segment: clamped scalar loads (cols >= W never read by taps)
                const int cb = cl4 + col;
                const int i0 = rowo + min(cb + 0, W - 1);
                const int i1 = rowo + min(cb + 1, W - 1);
                const int i2 = rowo + min(cb + 2, W - 1);
                const int i3 = rowo + min(cb + 3, W - 1);
#pragma unroll
                for (int ch = 0; ch < CHUNK; ++ch) {
                    const float* cp = base0 + (size_t)ch * plane;
                    v[ch].x = cp[i0]; v[ch].y = cp[i1];
                    v[ch].z = cp[i2]; v[ch].w = cp[i3];
                }
            }
#pragma unroll
            for (int ch = 0; ch < CHUNK; ++ch)
                *(float4*)(s_win + ch * CAP + loff) = v[ch];
        }
        __syncthreads();

        // ---- compute from LDS: 8x ds_read2_b32 + 16 FMA per element ----
        auto comp = [&](int e) -> float {
            const int c = e / 49, bin = e - c * 49;
            const int ph = bin / 7, pw = bin - ph * 7;
            const int cb = c * CAP;
            float acc = 0.0f;
#pragma unroll
            for (int sy = 0; sy < 2; ++sy) {
                const float4 yt = s_ytab[ph * 2 + sy];
                const int ra = cb + __float_as_int(yt.x);
                const int rb = cb + __float_as_int(yt.y);
                const float hy = yt.z, ly = yt.w;
#pragma unroll
                for (int sx = 0; sx < 2; ++sx) {
                    const float4 xt = s_xtab[pw * 2 + sx];
                    const int dx = __float_as_int(xt.x);
                    const float hx = xt.y, lx = xt.z;
                    const float a0 = s_win[ra + dx], a1 = s_win[ra + dx + 1];
                    const float b0 = s_win[rb + dx], b1 = s_win[rb + dx + 1];
                    acc += hy * (hx * a0 + lx * a1) + ly * (hx * b0 + lx * b1);
                }
            }
            return acc * 0.25f;
        };

        const float v0 = comp(t);
        float v1 = 0.0f;
        if (t < NELEM - 256) v1 = comp(t + 256);
        outbase[t] = v0;
        if (t < NELEM - 256) outbase[t + 256] = v1;

    } else {
        // ---- fallback (window > CAP; unreachable by geometry): global gather ----
        if (t < PD) {
            const int i = t >> 1, j = t & 1;
            const float yg = y1 + (float)i * bh + ((float)j + 0.5f) * bh * 0.5f;
            const float v = ((yg >= -1.0f) && (yg <= (float)H)) ? 1.0f : 0.0f;
            const float y = fminf(fmaxf(yg, 0.0f), (float)(H - 1));
            const int y0 = (int)floorf(y);
            const int y1i = min(y0 + 1, H - 1);
            const float ly = y - (float)y0;
            float4 r;
            r.x = __int_as_float(y0 * W);
            r.y = __int_as_float(y1i * W);
            r.z = (1.0f - ly) * v;
            r.w = ly * v;
            s_ytab[t] = r;
        } else if (t < 2 * PD) {
            const int tt = t - PD;
            const int i = tt >> 1, j = tt & 1;
            const float xg = x1 + (float)i * bw + ((float)j + 0.5f) * bw * 0.5f;
            const float v = ((xg >= -1.0f) && (xg <= (float)W)) ? 1.0f : 0.0f;
            const float x = fminf(fmaxf(xg, 0.0f), (float)(W - 1));
            const int x0 = (int)floorf(x);
            const int x1i = min(x0 + 1, W - 1);
            const float lx = x - (float)x0;
            float4 r;
            r.x = __int_as_float(x0);
            r.y = __int_as_float(x1i);
            r.z = (1.0f - lx) * v;
            r.w = lx * v;
            s_xtab[tt] = r;
        }
        __syncthreads();

        for (int e = t; e < NELEM; e += 256) {
            const int c = e / 49, bin = e - c * 49;
            const int ph = bin / 7, pw = bin - ph * 7;
            const float* fp = base0 + (size_t)c * plane;
            float acc = 0.0f;
#pragma unroll
            for (int sy = 0; sy < 2; ++sy) {
                const float4 yt = s_ytab[ph * 2 + sy];
                const int ro0 = __float_as_int(yt.x);
                const int ro1 = __float_as_int(yt.y);
                const float hy = yt.z, ly = yt.w;
#pragma unroll
                for (int sx = 0; sx < 2; ++sx) {
                    const float4 xt = s_xtab[pw * 2 + sx];
                    const int xa = __float_as_int(xt.x);
                    const int xb = __float_as_int(xt.y);
                    const float hx = xt.z, lx = xt.w;
                    acc += hy * (hx * fp[ro0 + xa] + lx * fp[ro0 + xb])
                         + ly * (hx * fp[ro1 + xa] + lx * fp[ro1 + xb]);
                }
            }
            outbase[e] = acc * 0.25f;
        }
    }
}

extern "C" void kernel_launch(void* const* d_in, const int* in_sizes, int n_in,
                              void* d_out, int out_size, void* d_ws, size_t ws_size,
                              hipStream_t stream) {
    const float* f0    = (const float*)d_in[0];
    const float* f1    = (const float*)d_in[1];
    const float* f2    = (const float*)d_in[2];
    const float* f3    = (const float*)d_in[3];
    const float* boxes = (const float*)d_in[4];
    const int*   ids   = (const int*)d_in[5];
    float* out = (float*)d_out;
    int*   order = (int*)d_ws;

    const int N = in_sizes[4] / 4;   // number of ROIs (1000)

    sort_kernel<<<1, 1024, 0, stream>>>(boxes, ids, order, N);

    dim3 grid(N, NCH / CHUNK);
    pooler_kernel<<<grid, 256, 0, stream>>>(f0, f1, f2, f3, boxes, ids, order, out, N);
}

// Round 7
// 231.025 us; speedup vs baseline: 1.1877x; 1.1877x over previous
//
#include <hip/hip_runtime.h>

#define OUTD 7
#define PD 14             // 14 sample coords per axis
#define NCH 256

// ---- transposed buffer layout (float offsets), [lvl][img][P][C] ----
#define TOFF0 0
#define TOFF1 20480000    // + 2*40000*256
#define TOFF2 25600000    // + 2*10000*256
#define TOFF3 26880000    // + 2*2500*256
#define TTOT  27200000    // + 2*625*256   (floats, = 108.8 MB)
#define TBASE_BYTES 16384

// ---------------- prepass: sort ROIs by (level, img, morton) ----------------
__global__ __launch_bounds__(1024)
void sort_kernel(const float* __restrict__ boxes,
                 const int*   __restrict__ img_ids,
                 int* __restrict__ order, int N)
{
    __shared__ unsigned long long kv[1024];
    const int t = threadIdx.x;

    unsigned int key = 0xFFFFFFFFu;
    if (t < N) {
        const float bx1 = boxes[t * 4 + 0];
        const float by1 = boxes[t * 4 + 1];
        const float bx2 = boxes[t * 4 + 2];
        const float by2 = boxes[t * 4 + 3];
        const float area = (bx2 - bx1) * (by2 - by1);
        const float s = sqrtf(area);
        float lvlf = floorf(4.0f + log2f(s / 224.0f + 1e-6f));
        lvlf = fminf(fmaxf(lvlf, 2.0f), 5.0f);
        const int lvl = (int)lvlf - 2;
        const float scales[4] = {0.25f, 0.125f, 0.0625f, 0.03125f};
        const float sc = scales[lvl];
        int cx = (int)(0.5f * (bx1 + bx2) * sc);
        int cy = (int)(0.5f * (by1 + by2) * sc);
        cx = min(max(cx, 0), 127);
        cy = min(max(cy, 0), 127);
        unsigned int m = 0;
#pragma unroll
        for (int b = 0; b < 7; ++b)
            m |= ((cy >> b) & 1u) << (2 * b + 1) | ((cx >> b) & 1u) << (2 * b);
        key = ((((unsigned)lvl << 1) | (unsigned)img_ids[t]) << 14) | m;
    }
    kv[t] = ((unsigned long long)key << 32) | (unsigned)t;
    __syncthreads();

    for (int k = 2; k <= 1024; k <<= 1) {
        for (int j = k >> 1; j > 0; j >>= 1) {
            const int ixj = t ^ j;
            if (ixj > t) {
                const bool up = ((t & k) == 0);
                const unsigned long long a = kv[t], b = kv[ixj];
                if ((a > b) == up) { kv[t] = b; kv[ixj] = a; }
            }
            __syncthreads();
        }
    }
    if (t < N) order[t] = (int)(kv[t] & 0xFFFFFFFFu);
}

// ---------------- transpose: [C][H][W] -> [P][C] per (img,lvl) ----------------
// 64x64 tiles via LDS [64][65] (bank-conflict-free both phases).
// grid.x = 6656 = 2 img * (625+157+40+10 p-tiles) * 4 c-tiles
__global__ __launch_bounds__(256)
void transpose_kernel(const float* __restrict__ f0, const float* __restrict__ f1,
                      const float* __restrict__ f2, const float* __restrict__ f3,
                      float* __restrict__ T)
{
    const int t = threadIdx.x;
    int id = blockIdx.x;
    const int ct = id & 3; id >>= 2;               // 0..1663
    const int img = (id >= 832) ? 1 : 0; if (img) id -= 832;
    int lvl, pt;
    if (id < 625)      { lvl = 0; pt = id; }
    else if (id < 782) { lvl = 1; pt = id - 625; }
    else if (id < 822) { lvl = 2; pt = id - 782; }
    else               { lvl = 3; pt = id - 822; }

    const int  Ps[4]   = {40000, 10000, 2500, 625};
    const long TO[4]   = {TOFF0, TOFF1, TOFF2, TOFF3};
    const float* feats[4] = {f0, f1, f2, f3};
    const int P = Ps[lvl];
    const float* __restrict__ src = feats[lvl] + (size_t)img * NCH * (size_t)P;
    float* __restrict__ dst = T + TO[lvl] + (size_t)img * (size_t)P * NCH;
    const int p0 = pt * 64, c0 = ct * 64;

    __shared__ float tile[64][65];
    const int a = t & 15, b = t >> 4;              // a:0..15, b:0..15

#pragma unroll
    for (int i = 0; i < 4; ++i) {
        const int cs = b + i * 16;                 // 0..63
        const int p4 = a * 4;                      // 0..60
        const float* sp = src + (size_t)(c0 + cs) * P + p0;
        float4 v;
        if ((P & 3) == 0 && p0 + p4 + 3 < P) {
            v = *(const float4*)(sp + p4);         // coalesced 16B, aligned (P%4==0)
        } else {
            const int m = P - 1 - p0;              // clamp (edge / P=625 misaligned)
            v.x = sp[min(p4 + 0, m)]; v.y = sp[min(p4 + 1, m)];
            v.z = sp[min(p4 + 2, m)]; v.w = sp[min(p4 + 3, m)];
        }
        tile[p4 + 0][cs] = v.x; tile[p4 + 1][cs] = v.y;
        tile[p4 + 2][cs] = v.z; tile[p4 + 3][cs] = v.w;
    }
    __syncthreads();
#pragma unroll
    for (int i = 0; i < 4; ++i) {
        const int ps = b + i * 16;
        const int c4 = a * 4;
        if (p0 + ps < P) {
            float4 v;
            v.x = tile[ps][c4 + 0]; v.y = tile[ps][c4 + 1];
            v.z = tile[ps][c4 + 2]; v.w = tile[ps][c4 + 3];
            *(float4*)(dst + (size_t)(p0 + ps) * NCH + c0 + c4) = v;  // coalesced 16B
        }
    }
}

// ---------------- pooler on transposed layout ----------------
// Block = 1 ROI, 256 threads = 4 waves. Lane owns channels 4l..4l+3.
// Every tap load = dwordx4, 64 lanes contiguous (1KB/instr, fully coalesced).
// Scattered VMEM lanes per output: 4 -> 0 (the round-0/3 limiter).
__global__ __launch_bounds__(256)
void pooler_t_kernel(const float* __restrict__ T,
                     const float* __restrict__ boxes,
                     const int*   __restrict__ img_ids,
                     const int*   __restrict__ order,
                     float* __restrict__ out, int N)
{
    int bx = blockIdx.x;
    int sidx;
    if ((N & 7) == 0) sidx = (bx & 7) * (N >> 3) + (bx >> 3);  // XCD-contiguous
    else              sidx = bx;
    const int roi = order[sidx];
    const int t = threadIdx.x;

    const float bx1 = boxes[roi * 4 + 0];
    const float by1 = boxes[roi * 4 + 1];
    const float bx2 = boxes[roi * 4 + 2];
    const float by2 = boxes[roi * 4 + 3];

    const float area = (bx2 - bx1) * (by2 - by1);
    const float s    = sqrtf(area);
    float lvlf = floorf(4.0f + log2f(s / 224.0f + 1e-6f));
    lvlf = fminf(fmaxf(lvlf, 2.0f), 5.0f);
    const int lvl = (int)lvlf - 2;   // 0..3

    const float scales[4] = {0.25f, 0.125f, 0.0625f, 0.03125f};
    const int   dims[4]   = {200, 100, 50, 25};
    const int   Ps[4]     = {40000, 10000, 2500, 625};
    const long  TO[4]     = {TOFF0, TOFF1, TOFF2, TOFF3};

    const float scale = scales[lvl];
    const int H = dims[lvl];
    const int W = H;
    const int img = img_ids[roi];
    const float* __restrict__ tb = T + TO[lvl] + (size_t)img * (size_t)Ps[lvl] * NCH;

    const float x1 = bx1 * scale, y1 = by1 * scale;
    const float x2 = bx2 * scale, y2 = by2 * scale;
    const float roi_w = fmaxf(x2 - x1, 1.0f);
    const float roi_h = fmaxf(y2 - y1, 1.0f);
    const float bw = roi_w / (float)OUTD;
    const float bh = roi_h / (float)OUTD;

    __shared__ float4 s_yt[PD];
    __shared__ float4 s_xt[PD];
    __shared__ float  s_out[49 * 260];   // [bin][260]: x4-aligned writes, pad vs 256

    if (t < PD) {
        const int i = t >> 1, j = t & 1;
        const float yg = y1 + (float)i * bh + ((float)j + 0.5f) * bh * 0.5f;
        const float v = ((yg >= -1.0f) && (yg <= (float)H)) ? 1.0f : 0.0f;
        const float y = fminf(fmaxf(yg, 0.0f), (float)(H - 1));
        const int y0 = (int)floorf(y);
        const int y1i = min(y0 + 1, H - 1);
        const float ly = y - (float)y0;
        float4 r;
        r.x = __int_as_float(y0 * W);
        r.y = __int_as_float(y1i * W);
        r.z = (1.0f - ly) * v;
        r.w = ly * v;
        s_yt[t] = r;
    } else if (t < 2 * PD) {
        const int tt = t - PD;
        const int i = tt >> 1, j = tt & 1;
        const float xg = x1 + (float)i * bw + ((float)j + 0.5f) * bw * 0.5f;
        const float v = ((xg >= -1.0f) && (xg <= (float)W)) ? 1.0f : 0.0f;
        const float x = fminf(fmaxf(xg, 0.0f), (float)(W - 1));
        const int x0 = (int)floorf(x);
        const int x1i = min(x0 + 1, W - 1);
        const float lx = x - (float)x0;
        float4 r;
        r.x = __int_as_float(x0);
        r.y = __int_as_float(x1i);
        r.z = (1.0f - lx) * v;
        r.w = lx * v;
        s_xt[tt] = r;
    }
    __syncthreads();

    const int lane = t & 63;
    const int w    = t >> 6;
    const int c4   = lane * 4;

    for (int bin = w; bin < 49; bin += 4) {
        const int ph = (bin * 37) >> 8;        // exact /7 for bin<49
        const int pw = bin - ph * 7;
        float4 acc = {0.0f, 0.0f, 0.0f, 0.0f};
#pragma unroll
        for (int sy = 0; sy < 2; ++sy) {
            const float4 yt = s_yt[ph * 2 + sy];
            const int r0 = __float_as_int(yt.x);
            const int r1 = __float_as_int(yt.y);
            const float hy = yt.z, ly = yt.w;
#pragma unroll
            for (int sx = 0; sx < 2; ++sx) {
                const float4 xt = s_xt[pw * 2 + sx];
                const int xa = __float_as_int(xt.x);
                const int xb = __float_as_int(xt.y);
                const float hx = xt.z, lx = xt.w;
                const float4 p00 = *(const float4*)(tb + ((size_t)(r0 + xa) << 8) + c4);
                const float4 p01 = *(const float4*)(tb + ((size_t)(r0 + xb) << 8) + c4);
                const float4 p10 = *(const float4*)(tb + ((size_t)(r1 + xa) << 8) + c4);
                const float4 p11 = *(const float4*)(tb + ((size_t)(r1 + xb) << 8) + c4);
                const float w00 = hy * hx, w01 = hy * lx, w10 = ly * hx, w11 = ly * lx;
                acc.x += w00 * p00.x + w01 * p01.x + w10 * p10.x + w11 * p11.x;
                acc.y += w00 * p00.y + w01 * p01.y + w10 * p10.y + w11 * p11.y;
                acc.z += w00 * p00.z + w01 * p01.z + w10 * p10.z + w11 * p11.z;
                acc.w += w00 * p00.w + w01 * p01.w + w10 * p10.w + w11 * p11.w;
            }
        }
        float4 r;
        r.x = acc.x * 0.25f; r.y = acc.y * 0.25f;
        r.z = acc.z * 0.25f; r.w = acc.w * 0.25f;
        *(float4*)(&s_out[bin * 260 + c4]) = r;
    }
    __syncthreads();

    // coalesced output: 12544 contiguous floats per ROI
    float* __restrict__ outbase = out + (size_t)roi * (NCH * 49);
#pragma unroll
    for (int i = 0; i < 49; ++i) {
        const int e = t + i * 256;
        const int c = (int)(((unsigned)e * 21400u) >> 20);   // exact /49 for e<12544
        const int bin = e - c * 49;
        outbase[e] = s_out[bin * 260 + c];
    }
}

// ---------------- legacy pooler (round-0 verbatim, 101 us): ws-size fallback ----------------
#define LCHUNK 32
__global__ __launch_bounds__(256)
void pooler_legacy(const float* __restrict__ f0,
                   const float* __restrict__ f1,
                   const float* __restrict__ f2,
                   const float* __restrict__ f3,
                   const float* __restrict__ boxes,
                   const int*   __restrict__ img_ids,
                   const int*   __restrict__ order,
                   float* __restrict__ out, int N)
{
    int bx = blockIdx.x;
    int sidx;
    if ((N & 7) == 0) sidx = (bx & 7) * (N >> 3) + (bx >> 3);
    else              sidx = bx;
    const int roi = order[sidx];

    const int c0  = blockIdx.y * LCHUNK;
    const int t   = threadIdx.x;

    const float bx1 = boxes[roi * 4 + 0];
    const float by1 = boxes[roi * 4 + 1];
    const float bx2 = boxes[roi * 4 + 2];
    const float by2 = boxes[roi * 4 + 3];

    const float area = (bx2 - bx1) * (by2 - by1);
    const float s    = sqrtf(area);
    float lvlf = floorf(4.0f + log2f(s / 224.0f + 1e-6f));
    lvlf = fminf(fmaxf(lvlf, 2.0f), 5.0f);
    const int lvl = (int)lvlf - 2;

    const float scales[4] = {0.25f, 0.125f, 0.0625f, 0.03125f};
    const int   dims[4]   = {200, 100, 50, 25};
    const float* feats[4] = {f0, f1, f2, f3};

    const float scale = scales[lvl];
    const int H = dims[lvl];
    const int W = H;
    const int plane = H * W;

    const int img = img_ids[roi];
    const float* __restrict__ base0 =
        feats[lvl] + (size_t)img * NCH * (size_t)plane + (size_t)c0 * plane;

    const float x1 = bx1 * scale, y1 = by1 * scale;
    const float x2 = bx2 * scale, y2 = by2 * scale;
    const float roi_w = fmaxf(x2 - x1, 1.0f);
    const float roi_h = fmaxf(y2 - y1, 1.0f);
    const float bw = roi_w / (float)OUTD;
    const float bh = roi_h / (float)OUTD;

    __shared__ float4 s_yt[PD];
    __shared__ float4 s_xt[PD];
    __shared__ float4 s_xw[OUTD];
    __shared__ int    s_xf[OUTD];
    __shared__ int    s_ok[OUTD];

    if (t < PD) {
        const int i = t >> 1, j = t & 1;
        const float yg = y1 + (float)i * bh + ((float)j + 0.5f) * bh * 0.5f;
        const float v = ((yg >= -1.0f) && (yg <= (float)H)) ? 1.0f : 0.0f;
        const float y = fminf(fmaxf(yg, 0.0f), (float)(H - 1));
        const int y0 = (int)floorf(y);
        const int y1i = min(y0 + 1, H - 1);
        const float ly = y - (float)y0;
        float4 r;
        r.x = __int_as_float(y0 * W);
        r.y = __int_as_float(y1i * W);
        r.z = (1.0f - ly) * v;
        r.w = ly * v;
        s_yt[t] = r;
    } else if (t < 2 * PD) {
        const int tt = t - PD;
        const int i = tt >> 1, j = tt & 1;
        const float xg = x1 + (float)i * bw + ((float)j + 0.5f) * bw * 0.5f;
        const float v = ((xg >= -1.0f) && (xg <= (float)W)) ? 1.0f : 0.0f;
        const float x = fminf(fmaxf(xg, 0.0f), (float)(W - 1));
        const int x0 = (int)floorf(x);
        const float lx = x - (float)x0;
        const float hx = 1.0f - lx;
        const int edge = (x0 == W - 1);
        float4 r;
        r.x = __int_as_float(min(x0, W - 2));
        r.y = edge ? 0.0f   : hx * v;
        r.z = edge ? hx * v : lx * v;
        r.w = 0.0f;
        s_xt[tt] = r;
    } else if (t < 2 * PD + OUTD) {
        const int pw = t - 2 * PD;
        float w[4] = {0.0f, 0.0f, 0.0f, 0.0f};
        int ca[2], cb[2];
        float hxv[2], lxv[2];
#pragma unroll
        for (int j = 0; j < 2; ++j) {
            const float xg = x1 + (float)pw * bw + ((float)j + 0.5f) * bw * 0.5f;
            const float v = ((xg >= -1.0f) && (xg <= (float)W)) ? 1.0f : 0.0f;
            const float x = fminf(fmaxf(xg, 0.0f), (float)(W - 1));
            const int x0 = (int)floorf(x);
            const float lx = x - (float)x0;
            ca[j] = x0;
            cb[j] = min(x0 + 1, W - 1);
            hxv[j] = (1.0f - lx) * v;
            lxv[j] = lx * v;
        }
        const int ok = (cb[1] - ca[0]) <= 3;
        int xf = min(ca[0], W - 4);
        if (xf < 0) xf = 0;
        w[(ca[0] - xf) & 3] += hxv[0];
        w[(cb[0] - xf) & 3] += lxv[0];
        w[(ca[1] - xf) & 3] += hxv[1];
        w[(cb[1] - xf) & 3] += lxv[1];
        float4 wv; wv.x = w[0]; wv.y = w[1]; wv.z = w[2]; wv.w = w[3];
        s_xw[pw] = wv;
        s_xf[pw] = xf;
        s_ok[pw] = ok;
    }
    __syncthreads();

    const bool fused = s_ok[0] && s_ok[1] && s_ok[2] && s_ok[3] &&
                       s_ok[4] && s_ok[5] && s_ok[6];

    float* __restrict__ outbase = out + ((size_t)roi * NCH + c0) * 49;

    if (fused) {
        auto g4 = [&](const float* __restrict__ fp, int ph, int pw, float4* P) {
            const float4 yt0 = s_yt[2 * ph];
            const float4 yt1 = s_yt[2 * ph + 1];
            const int xf = s_xf[pw];
            P[0] = *(const float4*)(fp + __float_as_int(yt0.x) + xf);
            P[1] = *(const float4*)(fp + __float_as_int(yt0.y) + xf);
            P[2] = *(const float4*)(fp + __float_as_int(yt1.x) + xf);
            P[3] = *(const float4*)(fp + __float_as_int(yt1.y) + xf);
        };
        auto r4 = [&](int ph, int pw, const float4* P) -> float {
            const float4 w   = s_xw[pw];
            const float4 yt0 = s_yt[2 * ph];
            const float4 yt1 = s_yt[2 * ph + 1];
            const float d0 = w.x * P[0].x + w.y * P[0].y + w.z * P[0].z + w.w * P[0].w;
            const float d1 = w.x * P[1].x + w.y * P[1].y + w.z * P[1].z + w.w * P[1].w;
            const float d2 = w.x * P[2].x + w.y * P[2].y + w.z * P[2].z + w.w * P[2].w;
            const float d3 = w.x * P[3].x + w.y * P[3].y + w.z * P[3].z + w.w * P[3].w;
            return yt0.z * d0 + yt0.w * d1 + yt1.z * d2 + yt1.w * d3;
        };
        {
            int eA[4], phA[4], pwA[4];
            const float* fpA[4];
#pragma unroll
            for (int j = 0; j < 4; ++j) {
                const int e = t + j * 256;
                const int c = e / 49, bin = e - c * 49;
                phA[j] = bin / 7;
                pwA[j] = bin - phA[j] * 7;
                eA[j]  = e;
                fpA[j] = base0 + (size_t)c * plane;
            }
            float4 P[4][4];
#pragma unroll
            for (int j = 0; j < 4; ++j) g4(fpA[j], phA[j], pwA[j], P[j]);
            __builtin_amdgcn_sched_barrier(0);
#pragma unroll
            for (int j = 0; j < 4; ++j)
                outbase[eA[j]] = r4(phA[j], pwA[j], P[j]) * 0.25f;
        }
        {
            int eA[2], phA[2], pwA[2];
            const float* fpA[2];
#pragma unroll
            for (int j = 0; j < 2; ++j) {
                const int e = t + (4 + j) * 256;
                const int c = e / 49, bin = e - c * 49;
                phA[j] = bin / 7;
                pwA[j] = bin - phA[j] * 7;
                eA[j]  = e;
                fpA[j] = base0 + (size_t)c * plane;
            }
            float4 P[2][4];
#pragma unroll
            for (int j = 0; j < 2; ++j) g4(fpA[j], phA[j], pwA[j], P[j]);
            __builtin_amdgcn_sched_barrier(0);
#pragma unroll
            for (int j = 0; j < 2; ++j)
                outbase[eA[j]] = r4(phA[j], pwA[j], P[j]) * 0.25f;
        }
        if (t < 32) {
            const int e = 1536 + t;
            const int c = e / 49, bin = e - c * 49;
            const int ph = bin / 7, pw = bin - ph * 7;
            const float* fp = base0 + (size_t)c * plane;
            float4 P[4];
            g4(fp, ph, pw, P);
            outbase[e] = r4(ph, pw, P) * 0.25f;
        }
    } else {
        auto gather = [&](const float* __restrict__ fp, int ph, int pw, float2* P) {
#pragma unroll
            for (int sy = 0; sy < 2; ++sy) {
                const float4 yt = s_yt[ph * 2 + sy];
                const int ro0 = __float_as_int(yt.x);
                const int ro1 = __float_as_int(yt.y);
#pragma unroll
                for (int sx = 0; sx < 2; ++sx) {
                    const float4 xt = s_xt[pw * 2 + sx];
                    const int xa = __float_as_int(xt.x);
                    P[(sy * 2 + sx) * 2 + 0] = *(const float2*)(fp + ro0 + xa);
                    P[(sy * 2 + sx) * 2 + 1] = *(const float2*)(fp + ro1 + xa);
                }
            }
        };
        auto reduce = [&](int ph, int pw, const float2* P) -> float {
            float acc = 0.0f;
#pragma unroll
            for (int sy = 0; sy < 2; ++sy) {
                const float4 yt = s_yt[ph * 2 + sy];
                const float hy = yt.z, ly = yt.w;
#pragma unroll
                for (int sx = 0; sx < 2; ++sx) {
                    const float4 xt = s_xt[pw * 2 + sx];
                    const float wlo = xt.y, whi = xt.z;
                    const float2 p0 = P[(sy * 2 + sx) * 2 + 0];
                    const float2 p1 = P[(sy * 2 + sx) * 2 + 1];
                    acc += hy * (wlo * p0.x + whi * p0.y)
                         + ly * (wlo * p1.x + whi * p1.y);
                }
            }
            return acc;
        };
#pragma unroll
        for (int kk = 0; kk < 2; ++kk) {
            int eA[3], phA[3], pwA[3];
            const float* fpA[3];
#pragma unroll
            for (int j = 0; j < 3; ++j) {
                const int e = t + (kk * 3 + j) * 256;
                const int c = e / 49, bin = e - c * 49;
                phA[j] = bin / 7;
                pwA[j] = bin - phA[j] * 7;
                eA[j]  = e;
                fpA[j] = base0 + (size_t)c * plane;
            }
            float2 P[3][8];
#pragma unroll
            for (int j = 0; j < 3; ++j) gather(fpA[j], phA[j], pwA[j], P[j]);
            __builtin_amdgcn_sched_barrier(0);
#pragma unroll
            for (int j = 0; j < 3; ++j)
                outbase[eA[j]] = reduce(phA[j], pwA[j], P[j]) * 0.25f;
        }
        if (t < 32) {
            const int e = 1536 + t;
            const int c = e / 49, bin = e - c * 49;
            const int ph = bin / 7, pw = bin - ph * 7;
            const float* fp = base0 + (size_t)c * plane;
            float2 P[8];
            gather(fp, ph, pw, P);
            outbase[e] = reduce(ph, pw, P) * 0.25f;
        }
    }
}

extern "C" void kernel_launch(void* const* d_in, const int* in_sizes, int n_in,
                              void* d_out, int out_size, void* d_ws, size_t ws_size,
                              hipStream_t stream) {
    const float* f0    = (const float*)d_in[0];
    const float* f1    = (const float*)d_in[1];
    const float* f2    = (const float*)d_in[2];
    const float* f3    = (const float*)d_in[3];
    const float* boxes = (const float*)d_in[4];
    const int*   ids   = (const int*)d_in[5];
    float* out = (float*)d_out;
    int*   order = (int*)d_ws;

    const int N = in_sizes[4] / 4;   // number of ROIs (1000)

    const size_t need = (size_t)TBASE_BYTES + (size_t)TTOT * sizeof(float);

    sort_kernel<<<1, 1024, 0, stream>>>(boxes, ids, order, N);

    if (ws_size >= need) {
        float* T = (float*)((char*)d_ws + TBASE_BYTES);
        transpose_kernel<<<6656, 256, 0, stream>>>(f0, f1, f2, f3, T);
        pooler_t_kernel<<<N, 256, 0, stream>>>(T, boxes, ids, order, out, N);
    } else {
        dim3 grid(N, NCH / LCHUNK);
        pooler_legacy<<<grid, 256, 0, stream>>>(f0, f1, f2, f3, boxes, ids, order, out, N);
    }
}

// Round 9
// 229.469 us; speedup vs baseline: 1.1958x; 1.0068x over previous
//
#include <hip/hip_runtime.h>

#define OUTD 7
#define PD 14             // 14 sample coords per axis
#define NCH 256

// ---- transposed buffer layout (float offsets), [lvl][img][P][C] ----
#define TOFF0 0
#define TOFF1 20480000    // + 2*40000*256
#define TOFF2 25600000    // + 2*10000*256
#define TOFF3 26880000    // + 2*2500*256
#define TTOT  27200000    // + 2*625*256   (floats, = 108.8 MB)
#define TBASE_BYTES 16384

// ---------------- prepass: sort ROIs by (level, img, morton) ----------------
__global__ __launch_bounds__(1024)
void sort_kernel(const float* __restrict__ boxes,
                 const int*   __restrict__ img_ids,
                 int* __restrict__ order, int N)
{
    __shared__ unsigned long long kv[1024];
    const int t = threadIdx.x;

    unsigned int key = 0xFFFFFFFFu;
    if (t < N) {
        const float bx1 = boxes[t * 4 + 0];
        const float by1 = boxes[t * 4 + 1];
        const float bx2 = boxes[t * 4 + 2];
        const float by2 = boxes[t * 4 + 3];
        const float area = (bx2 - bx1) * (by2 - by1);
        const float s = sqrtf(area);
        float lvlf = floorf(4.0f + log2f(s / 224.0f + 1e-6f));
        lvlf = fminf(fmaxf(lvlf, 2.0f), 5.0f);
        const int lvl = (int)lvlf - 2;
        const float scales[4] = {0.25f, 0.125f, 0.0625f, 0.03125f};
        const float sc = scales[lvl];
        int cx = (int)(0.5f * (bx1 + bx2) * sc);
        int cy = (int)(0.5f * (by1 + by2) * sc);
        cx = min(max(cx, 0), 127);
        cy = min(max(cy, 0), 127);
        unsigned int m = 0;
#pragma unroll
        for (int b = 0; b < 7; ++b)
            m |= ((cy >> b) & 1u) << (2 * b + 1) | ((cx >> b) & 1u) << (2 * b);
        key = ((((unsigned)lvl << 1) | (unsigned)img_ids[t]) << 14) | m;
    }
    kv[t] = ((unsigned long long)key << 32) | (unsigned)t;
    __syncthreads();

    for (int k = 2; k <= 1024; k <<= 1) {
        for (int j = k >> 1; j > 0; j >>= 1) {
            const int ixj = t ^ j;
            if (ixj > t) {
                const bool up = ((t & k) == 0);
                const unsigned long long a = kv[t], b = kv[ixj];
                if ((a > b) == up) { kv[t] = b; kv[ixj] = a; }
            }
            __syncthreads();
        }
    }
    if (t < N) order[t] = (int)(kv[t] & 0xFFFFFFFFu);
}

// ---------------- transpose: [C][H][W] -> [P][C] per (img,lvl) ----------------
// Round-7 lesson: 64x64 tiles gave 4x256B segments BOTH sides -> 2.5 TB/s
// (31% peak), 66us. New tile: 64p x 256c (full channel dim), LDS [64][260].
// Phase-2 writes whole [P][C] rows: 64 lanes x float4 = 1KB contiguous per
// wave-instr. Phase-2 LDS reads: full-row b128, conflict-free, 16B-aligned
// (stride 260*4=1040). Phase-1 keeps 4x256B reads (L3-cushioned) + 8-deep ILP;
// its scalar LDS writes are ~8-way conflicted (hidden under load latency).
// grid.x = 1664 = 2 img * (625+157+40+10 p-tiles)
__global__ __launch_bounds__(512)
void transpose_kernel(const float* __restrict__ f0, const float* __restrict__ f1,
                      const float* __restrict__ f2, const float* __restrict__ f3,
                      float* __restrict__ T)
{
    const int t = threadIdx.x;
    int id = blockIdx.x;                           // 0..1663
    const int img = (id >= 832) ? 1 : 0; if (img) id -= 832;
    int lvl, pt;
    if (id < 625)      { lvl = 0; pt = id; }
    else if (id < 782) { lvl = 1; pt = id - 625; }
    else if (id < 822) { lvl = 2; pt = id - 782; }
    else               { lvl = 3; pt = id - 822; }

    const int  Ps[4]   = {40000, 10000, 2500, 625};
    const long TO[4]   = {TOFF0, TOFF1, TOFF2, TOFF3};
    const float* feats[4] = {f0, f1, f2, f3};
    const int P = Ps[lvl];
    const float* __restrict__ src = feats[lvl] + (size_t)img * NCH * (size_t)P;
    float* __restrict__ dst = T + TO[lvl] + (size_t)img * (size_t)P * NCH;
    const int p0 = pt * 64;

    __shared__ float tile[64][260];   // stride 260: row*4B = 1040, 16B-aligned

    // ---- phase 1: load 4 p-floats per channel, 8 channels per thread ----
    const int a  = t & 15;            // p4-group
    const int cg = t >> 4;            // 0..31
    const int p4 = a * 4;

#pragma unroll
    for (int i = 0; i < 8; ++i) {
        const int cs = cg + 32 * i;   // 0..255
        const float* sp = src + (size_t)cs * P + p0;
        float4 v;
        if (((P & 3) == 0) && (p0 + p4 + 3 < P)) {
            v = *(const float4*)(sp + p4);       // coalesced 16B, aligned
        } else {
            const int m = P - 1 - p0;            // clamp (edge tile / P=625)
            v.x = sp[min(p4 + 0, m)]; v.y = sp[min(p4 + 1, m)];
            v.z = sp[min(p4 + 2, m)]; v.w = sp[min(p4 + 3, m)];
        }
        tile[p4 + 0][cs] = v.x;
        tile[p4 + 1][cs] = v.y;
        tile[p4 + 2][cs] = v.z;
        tile[p4 + 3][cs] = v.w;
    }
    __syncthreads();

    // ---- phase 2: write full [P][C] rows, 1KB contiguous per wave ----
    const int c4 = (t & 63) * 4;
    const int w  = t >> 6;            // 0..7
#pragma unroll
    for (int i = 0; i < 8; ++i) {
        const int p = w + 8 * i;      // 0..63
        if (p0 + p < P) {
            float4 v;
            v.x = tile[p][c4 + 0]; v.y = tile[p][c4 + 1];
            v.z = tile[p][c4 + 2]; v.w = tile[p][c4 + 3];
            *(float4*)(dst + (size_t)(p0 + p) * NCH + c4) = v;
        }
    }
}

// ---------------- pooler on transposed layout ----------------
// Block = 1 ROI, 256 threads = 4 waves. Lane owns channels 4l..4l+3.
// Every tap load = dwordx4, 64 lanes contiguous (1KB/instr, fully coalesced).
// Scattered VMEM lanes per output: 4 -> 0 (the round-0/3 limiter).
// Measured round 7: ~42us (vs 101us scatter pooler).
__global__ __launch_bounds__(256)
void pooler_t_kernel(const float* __restrict__ T,
                     const float* __restrict__ boxes,
                     const int*   __restrict__ img_ids,
                     const int*   __restrict__ order,
                     float* __restrict__ out, int N)
{
    int bx = blockIdx.x;
    int sidx;
    if ((N & 7) == 0) sidx = (bx & 7) * (N >> 3) + (bx >> 3);  // XCD-contiguous
    else              sidx = bx;
    const int roi = order[sidx];
    const int t = threadIdx.x;

    const float bx1 = boxes[roi * 4 + 0];
    const float by1 = boxes[roi * 4 + 1];
    const float bx2 = boxes[roi * 4 + 2];
    const float by2 = boxes[roi * 4 + 3];

    const float area = (bx2 - bx1) * (by2 - by1);
    const float s    = sqrtf(area);
    float lvlf = floorf(4.0f + log2f(s / 224.0f + 1e-6f));
    lvlf = fminf(fmaxf(lvlf, 2.0f), 5.0f);
    const int lvl = (int)lvlf - 2;   // 0..3

    const float scales[4] = {0.25f, 0.125f, 0.0625f, 0.03125f};
    const int   dims[4]   = {200, 100, 50, 25};
    const int   Ps[4]     = {40000, 10000, 2500, 625};
    const long  TO[4]     = {TOFF0, TOFF1, TOFF2, TOFF3};

    const float scale = scales[lvl];
    const int H = dims[lvl];
    const int W = H;
    const int img = img_ids[roi];
    const float* __restrict__ tb = T + TO[lvl] + (size_t)img * (size_t)Ps[lvl] * NCH;

    const float x1 = bx1 * scale, y1 = by1 * scale;
    const float x2 = bx2 * scale, y2 = by2 * scale;
    const float roi_w = fmaxf(x2 - x1, 1.0f);
    const float roi_h = fmaxf(y2 - y1, 1.0f);
    const float bw = roi_w / (float)OUTD;
    const float bh = roi_h / (float)OUTD;

    __shared__ float4 s_yt[PD];
    __shared__ float4 s_xt[PD];
    __shared__ float  s_out[49 * 260];   // [bin][260]: x4-aligned writes, pad vs 256

    if (t < PD) {
        const int i = t >> 1, j = t & 1;
        const float yg = y1 + (float)i * bh + ((float)j + 0.5f) * bh * 0.5f;
        const float v = ((yg >= -1.0f) && (yg <= (float)H)) ? 1.0f : 0.0f;
        const float y = fminf(fmaxf(yg, 0.0f), (float)(H - 1));
        const int y0 = (int)floorf(y);
        const int y1i = min(y0 + 1, H - 1);
        const float ly = y - (float)y0;
        float4 r;
        r.x = __int_as_float(y0 * W);
        r.y = __int_as_float(y1i * W);
        r.z = (1.0f - ly) * v;
        r.w = ly * v;
        s_yt[t] = r;
    } else if (t < 2 * PD) {
        const int tt = t - PD;
        const int i = tt >> 1, j = tt & 1;
        const float xg = x1 + (float)i * bw + ((float)j + 0.5f) * bw * 0.5f;
        const float v = ((xg >= -1.0f) && (xg <= (float)W)) ? 1.0f : 0.0f;
        const float x = fminf(fmaxf(xg, 0.0f), (float)(W - 1));
        const int x0 = (int)floorf(x);
        const int x1i = min(x0 + 1, W - 1);
        const float lx = x - (float)x0;
        float4 r;
        r.x = __int_as_float(x0);
        r.y = __int_as_float(x1i);
        r.z = (1.0f - lx) * v;
        r.w = lx * v;
        s_xt[tt] = r;
    }
    __syncthreads();

    const int lane = t & 63;
    const int w    = t >> 6;
    const int c4   = lane * 4;

    for (int bin = w; bin < 49; bin += 4) {
        const int ph = (bin * 37) >> 8;        // exact /7 for bin<49
        const int pw = bin - ph * 7;
        float4 acc = {0.0f, 0.0f, 0.0f, 0.0f};
#pragma unroll
        for (int sy = 0; sy < 2; ++sy) {
            const float4 yt = s_yt[ph * 2 + sy];
            const int r0 = __float_as_int(yt.x);
            const int r1 = __float_as_int(yt.y);
            const float hy = yt.z, ly = yt.w;
#pragma unroll
            for (int sx = 0; sx < 2; ++sx) {
                const float4 xt = s_xt[pw * 2 + sx];
                const int xa = __float_as_int(xt.x);
                const int xb = __float_as_int(xt.y);
                const float hx = xt.z, lx = xt.w;
                const float4 p00 = *(const float4*)(tb + ((size_t)(r0 + xa) << 8) + c4);
                const float4 p01 = *(const float4*)(tb + ((size_t)(r0 + xb) << 8) + c4);
                const float4 p10 = *(const float4*)(tb + ((size_t)(r1 + xa) << 8) + c4);
                const float4 p11 = *(const float4*)(tb + ((size_t)(r1 + xb) << 8) + c4);
                const float w00 = hy * hx, w01 = hy * lx, w10 = ly * hx, w11 = ly * lx;
                acc.x += w00 * p00.x + w01 * p01.x + w10 * p10.x + w11 * p11.x;
                acc.y += w00 * p00.y + w01 * p01.y + w10 * p10.y + w11 * p11.y;
                acc.z += w00 * p00.z + w01 * p01.z + w10 * p10.z + w11 * p11.z;
                acc.w += w00 * p00.w + w01 * p01.w + w10 * p10.w + w11 * p11.w;
            }
        }
        float4 r;
        r.x = acc.x * 0.25f; r.y = acc.y * 0.25f;
        r.z = acc.z * 0.25f; r.w = acc.w * 0.25f;
        *(float4*)(&s_out[bin * 260 + c4]) = r;
    }
    __syncthreads();

    // coalesced output: 12544 contiguous floats per ROI
    float* __restrict__ outbase = out + (size_t)roi * (NCH * 49);
#pragma unroll
    for (int i = 0; i < 49; ++i) {
        const int e = t + i * 256;
        const int c = (int)(((unsigned)e * 21400u) >> 20);   // exact /49 for e<12544
        const int bin = e - c * 49;
        outbase[e] = s_out[bin * 260 + c];
    }
}

// ---------------- legacy pooler (round-0 verbatim, 101 us): ws-size fallback ----------------
#define LCHUNK 32
__global__ __launch_bounds__(256)
void pooler_legacy(const float* __restrict__ f0,
                   const float* __restrict__ f1,
                   const float* __restrict__ f2,
                   const float* __restrict__ f3,
                   const float* __restrict__ boxes,
                   const int*   __restrict__ img_ids,
                   const int*   __restrict__ order,
                   float* __restrict__ out, int N)
{
    int bx = blockIdx.x;
    int sidx;
    if ((N & 7) == 0) sidx = (bx & 7) * (N >> 3) + (bx >> 3);
    else              sidx = bx;
    const int roi = order[sidx];

    const int c0  = blockIdx.y * LCHUNK;
    const int t   = threadIdx.x;

    const float bx1 = boxes[roi * 4 + 0];
    const float by1 = boxes[roi * 4 + 1];
    const float bx2 = boxes[roi * 4 + 2];
    const float by2 = boxes[roi * 4 + 3];

    const float area = (bx2 - bx1) * (by2 - by1);
    const float s    = sqrtf(area);
    float lvlf = floorf(4.0f + log2f(s / 224.0f + 1e-6f));
    lvlf = fminf(fmaxf(lvlf, 2.0f), 5.0f);
    const int lvl = (int)lvlf - 2;

    const float scales[4] = {0.25f, 0.125f, 0.0625f, 0.03125f};
    const int   dims[4]   = {200, 100, 50, 25};
    const float* feats[4] = {f0, f1, f2, f3};

    const float scale = scales[lvl];
    const int H = dims[lvl];
    const int W = H;
    const int plane = H * W;

    const int img = img_ids[roi];
    const float* __restrict__ base0 =
        feats[lvl] + (size_t)img * NCH * (size_t)plane + (size_t)c0 * plane;

    const float x1 = bx1 * scale, y1 = by1 * scale;
    const float x2 = bx2 * scale, y2 = by2 * scale;
    const float roi_w = fmaxf(x2 - x1, 1.0f);
    const float roi_h = fmaxf(y2 - y1, 1.0f);
    const float bw = roi_w / (float)OUTD;
    const float bh = roi_h / (float)OUTD;

    __shared__ float4 s_yt[PD];
    __shared__ float4 s_xt[PD];
    __shared__ float4 s_xw[OUTD];
    __shared__ int    s_xf[OUTD];
    __shared__ int    s_ok[OUTD];

    if (t < PD) {
        const int i = t >> 1, j = t & 1;
        const float yg = y1 + (float)i * bh + ((float)j + 0.5f) * bh * 0.5f;
        const float v = ((yg >= -1.0f) && (yg <= (float)H)) ? 1.0f : 0.0f;
        const float y = fminf(fmaxf(yg, 0.0f), (float)(H - 1));
        const int y0 = (int)floorf(y);
        const int y1i = min(y0 + 1, H - 1);
        const float ly = y - (float)y0;
        float4 r;
        r.x = __int_as_float(y0 * W);
        r.y = __int_as_float(y1i * W);
        r.z = (1.0f - ly) * v;
        r.w = ly * v;
        s_yt[t] = r;
    } else if (t < 2 * PD) {
        const int tt = t - PD;
        const int i = tt >> 1, j = tt & 1;
        const float xg = x1 + (float)i * bw + ((float)j + 0.5f) * bw * 0.5f;
        const float v = ((xg >= -1.0f) && (xg <= (float)W)) ? 1.0f : 0.0f;
        const float x = fminf(fmaxf(xg, 0.0f), (float)(W - 1));
        const int x0 = (int)floorf(x);
        const float lx = x - (float)x0;
        const float hx = 1.0f - lx;
        const int edge = (x0 == W - 1);
        float4 r;
        r.x = __int_as_float(min(x0, W - 2));
        r.y = edge ? 0.0f   : hx * v;
        r.z = edge ? hx * v : lx * v;
        r.w = 0.0f;
        s_xt[tt] = r;
    } else if (t < 2 * PD + OUTD) {
        const int pw = t - 2 * PD;
        float w[4] = {0.0f, 0.0f, 0.0f, 0.0f};
        int ca[2], cb[2];
        float hxv[2], lxv[2];
#pragma unroll
        for (int j = 0; j < 2; ++j) {
            const float xg = x1 + (float)pw * bw + ((float)j + 0.5f) * bw * 0.5f;
            const float v = ((xg >= -1.0f) && (xg <= (float)W)) ? 1.0f : 0.0f;
            const float x = fminf(fmaxf(xg, 0.0f), (float)(W - 1));
            const int x0 = (int)floorf(x);
            const float lx = x - (float)x0;
            ca[j] = x0;
            cb[j] = min(x0 + 1, W - 1);
            hxv[j] = (1.0f - lx) * v;
            lxv[j] = lx * v;
        }
        const int ok = (cb[1] - ca[0]) <= 3;
        int xf = min(ca[0], W - 4);
        if (xf < 0) xf = 0;
        w[(ca[0] - xf) & 3] += hxv[0];
        w[(cb[0] - xf) & 3] += lxv[0];
        w[(ca[1] - xf) & 3] += hxv[1];
        w[(cb[1] - xf) & 3] += lxv[1];
        float4 wv; wv.x = w[0]; wv.y = w[1]; wv.z = w[2]; wv.w = w[3];
        s_xw[pw] = wv;
        s_xf[pw] = xf;
        s_ok[pw] = ok;
    }
    __syncthreads();

    const bool fused = s_ok[0] && s_ok[1] && s_ok[2] && s_ok[3] &&
                       s_ok[4] && s_ok[5] && s_ok[6];

    float* __restrict__ outbase = out + ((size_t)roi * NCH + c0) * 49;

    if (fused) {
        auto g4 = [&](const float* __restrict__ fp, int ph, int pw, float4* P) {
            const float4 yt0 = s_yt[2 * ph];
            const float4 yt1 = s_yt[2 * ph + 1];
            const int xf = s_xf[pw];
            P[0] = *(const float4*)(fp + __float_as_int(yt0.x) + xf);
            P[1] = *(const float4*)(fp + __float_as_int(yt0.y) + xf);
            P[2] = *(const float4*)(fp + __float_as_int(yt1.x) + xf);
            P[3] = *(const float4*)(fp + __float_as_int(yt1.y) + xf);
        };
        auto r4 = [&](int ph, int pw, const float4* P) -> float {
            const float4 w   = s_xw[pw];
            const float4 yt0 = s_yt[2 * ph];
            const float4 yt1 = s_yt[2 * ph + 1];
            const float d0 = w.x * P[0].x + w.y * P[0].y + w.z * P[0].z + w.w * P[0].w;
            const float d1 = w.x * P[1].x + w.y * P[1].y + w.z * P[1].z + w.w * P[1].w;
            const float d2 = w.x * P[2].x + w.y * P[2].y + w.z * P[2].z + w.w * P[2].w;
            const float d3 = w.x * P[3].x + w.y * P[3].y + w.z * P[3].z + w.w * P[3].w;
            return yt0.z * d0 + yt0.w * d1 + yt1.z * d2 + yt1.w * d3;
        };
        {
            int eA[4], phA[4], pwA[4];
            const float* fpA[4];
#pragma unroll
            for (int j = 0; j < 4; ++j) {
                const int e = t + j * 256;
                const int c = e / 49, bin = e - c * 49;
                phA[j] = bin / 7;
                pwA[j] = bin - phA[j] * 7;
                eA[j]  = e;
                fpA[j] = base0 + (size_t)c * plane;
            }
            float4 P[4][4];
#pragma unroll
            for (int j = 0; j < 4; ++j) g4(fpA[j], phA[j], pwA[j], P[j]);
            __builtin_amdgcn_sched_barrier(0);
#pragma unroll
            for (int j = 0; j < 4; ++j)
                outbase[eA[j]] = r4(phA[j], pwA[j], P[j]) * 0.25f;
        }
        {
            int eA[2], phA[2], pwA[2];
            const float* fpA[2];
#pragma unroll
            for (int j = 0; j < 2; ++j) {
                const int e = t + (4 + j) * 256;
                const int c = e / 49, bin = e - c * 49;
                phA[j] = bin / 7;
                pwA[j] = bin - phA[j] * 7;
                eA[j]  = e;
                fpA[j] = base0 + (size_t)c * plane;
            }
            float4 P[2][4];
#pragma unroll
            for (int j = 0; j < 2; ++j) g4(fpA[j], phA[j], pwA[j], P[j]);
            __builtin_amdgcn_sched_barrier(0);
#pragma unroll
            for (int j = 0; j < 2; ++j)
                outbase[eA[j]] = r4(phA[j], pwA[j], P[j]) * 0.25f;
        }
        if (t < 32) {
            const int e = 1536 + t;
            const int c = e / 49, bin = e - c * 49;
            const int ph = bin / 7, pw = bin - ph * 7;
            const float* fp = base0 + (size_t)c * plane;
            float4 P[4];
            g4(fp, ph, pw, P);
            outbase[e] = r4(ph, pw, P) * 0.25f;
        }
    } else {
        auto gather = [&](const float* __restrict__ fp, int ph, int pw, float2* P) {
#pragma unroll
            for (int sy = 0; sy < 2; ++sy) {
                const float4 yt = s_yt[ph * 2 + sy];
                const int ro0 = __float_as_int(yt.x);
                const int ro1 = __float_as_int(yt.y);
#pragma unroll
                for (int sx = 0; sx < 2; ++sx) {
                    const float4 xt = s_xt[pw * 2 + sx];
                    const int xa = __float_as_int(xt.x);
                    P[(sy * 2 + sx) * 2 + 0] = *(const float2*)(fp + ro0 + xa);
                    P[(sy * 2 + sx) * 2 + 1] = *(const float2*)(fp + ro1 + xa);
                }
            }
        };
        auto reduce = [&](int ph, int pw, const float2* P) -> float {
            float acc = 0.0f;
#pragma unroll
            for (int sy = 0; sy < 2; ++sy) {
                const float4 yt = s_yt[ph * 2 + sy];
                const float hy = yt.z, ly = yt.w;
#pragma unroll
                for (int sx = 0; sx < 2; ++sx) {
                    const float4 xt = s_xt[pw * 2 + sx];
                    const float wlo = xt.y, whi = xt.z;
                    const float2 p0 = P[(sy * 2 + sx) * 2 + 0];
                    const float2 p1 = P[(sy * 2 + sx) * 2 + 1];
                    acc += hy * (wlo * p0.x + whi * p0.y)
                         + ly * (wlo * p1.x + whi * p1.y);
                }
            }
            return acc;
        };
#pragma unroll
        for (int kk = 0; kk < 2; ++kk) {
            int eA[3], phA[3], pwA[3];
            const float* fpA[3];
#pragma unroll
            for (int j = 0; j < 3; ++j) {
                const int e = t + (kk * 3 + j) * 256;
                const int c = e / 49, bin = e - c * 49;
                phA[j] = bin / 7;
                pwA[j] = bin - phA[j] * 7;
                eA[j]  = e;
                fpA[j] = base0 + (size_t)c * plane;
            }
            float2 P[3][8];
#pragma unroll
            for (int j = 0; j < 3; ++j) gather(fpA[j], phA[j], pwA[j], P[j]);
            __builtin_amdgcn_sched_barrier(0);
#pragma unroll
            for (int j = 0; j < 3; ++j)
                outbase[eA[j]] = reduce(phA[j], pwA[j], P[j]) * 0.25f;
        }
        if (t < 32) {
            const int e = 1536 + t;
            const int c = e / 49, bin = e - c * 49;
            const int ph = bin / 7, pw = bin - ph * 7;
            const float* fp = base0 + (size_t)c * plane;
            float2 P[8];
            gather(fp, ph, pw, P);
            outbase[e] = reduce(ph, pw, P) * 0.25f;
        }
    }
}

extern "C" void kernel_launch(void* const* d_in, const int* in_sizes, int n_in,
                              void* d_out, int out_size, void* d_ws, size_t ws_size,
                              hipStream_t stream) {
    const float* f0    = (const float*)d_in[0];
    const float* f1    = (const float*)d_in[1];
    const float* f2    = (const float*)d_in[2];
    const float* f3    = (const float*)d_in[3];
    const float* boxes = (const float*)d_in[4];
    const int*   ids   = (const int*)d_in[5];
    float* out = (float*)d_out;
    int*   order = (int*)d_ws;

    const int N = in_sizes[4] / 4;   // number of ROIs (1000)

    const size_t need = (size_t)TBASE_BYTES + (size_t)TTOT * sizeof(float);

    sort_kernel<<<1, 1024, 0, stream>>>(boxes, ids, order, N);

    if (ws_size >= need) {
        float* T = (float*)((char*)d_ws + TBASE_BYTES);
        transpose_kernel<<<1664, 512, 0, stream>>>(f0, f1, f2, f3, T);
        pooler_t_kernel<<<N, 256, 0, stream>>>(T, boxes, ids, order, out, N);
    } else {
        dim3 grid(N, NCH / LCHUNK);
        pooler_legacy<<<grid, 256, 0, stream>>>(f0, f1, f2, f3, boxes, ids, order, out, N);
    }
}

// Round 10
// 217.601 us; speedup vs baseline: 1.2610x; 1.0545x over previous
//
#include <hip/hip_runtime.h>
#include <hip/hip_fp16.h>

#define OUTD 7
#define PD 14             // 14 sample coords per axis
#define NCH 256

// ---- transposed buffer layout (HALF-element offsets), [lvl][img][P][C] ----
#define TOFF0 0
#define TOFF1 20480000    // + 2*40000*256
#define TOFF2 25600000    // + 2*10000*256
#define TOFF3 26880000    // + 2*2500*256
#define TTOT  27200000    // halfs (= 54.4 MB)
#define TBASE_BYTES 16384

// ---------------- prepass: sort ROIs by (level, img, morton) ----------------
__global__ __launch_bounds__(1024)
void sort_kernel(const float* __restrict__ boxes,
                 const int*   __restrict__ img_ids,
                 int* __restrict__ order, int N)
{
    __shared__ unsigned long long kv[1024];
    const int t = threadIdx.x;

    unsigned int key = 0xFFFFFFFFu;
    if (t < N) {
        const float bx1 = boxes[t * 4 + 0];
        const float by1 = boxes[t * 4 + 1];
        const float bx2 = boxes[t * 4 + 2];
        const float by2 = boxes[t * 4 + 3];
        const float area = (bx2 - bx1) * (by2 - by1);
        const float s = sqrtf(area);
        float lvlf = floorf(4.0f + log2f(s / 224.0f + 1e-6f));
        lvlf = fminf(fmaxf(lvlf, 2.0f), 5.0f);
        const int lvl = (int)lvlf - 2;
        const float scales[4] = {0.25f, 0.125f, 0.0625f, 0.03125f};
        const float sc = scales[lvl];
        int cx = (int)(0.5f * (bx1 + bx2) * sc);
        int cy = (int)(0.5f * (by1 + by2) * sc);
        cx = min(max(cx, 0), 127);
        cy = min(max(cy, 0), 127);
        unsigned int m = 0;
#pragma unroll
        for (int b = 0; b < 7; ++b)
            m |= ((cy >> b) & 1u) << (2 * b + 1) | ((cx >> b) & 1u) << (2 * b);
        key = ((((unsigned)lvl << 1) | (unsigned)img_ids[t]) << 14) | m;
    }
    kv[t] = ((unsigned long long)key << 32) | (unsigned)t;
    __syncthreads();

    for (int k = 2; k <= 1024; k <<= 1) {
        for (int j = k >> 1; j > 0; j >>= 1) {
            const int ixj = t ^ j;
            if (ixj > t) {
                const bool up = ((t & k) == 0);
                const unsigned long long a = kv[t], b = kv[ixj];
                if ((a > b) == up) { kv[t] = b; kv[ixj] = a; }
            }
            __syncthreads();
        }
    }
    if (t < N) order[t] = (int)(kv[t] & 0xFFFFFFFFu);
}

// ---------------- transpose: [C][H][W] f32 -> [P][C] f16 per (img,lvl) ------
// Round-9 lesson: write-pattern granularity is NOT the limit (4x256B == 1KB
// contiguous, both 65us). Model: L3 thrash (inputs 109 + T-f32 109 + out 49 =
// 267MB > 256MB IC) + write-heavy HBM traffic. fp16 T halves writes (106->53MB)
// and makes the working set (212MB) L3-resident.
// grid.x = 1664 = 2 img * (625+157+40+10 p-tiles)
__global__ __launch_bounds__(512)
void transpose_kernel(const float* __restrict__ f0, const float* __restrict__ f1,
                      const float* __restrict__ f2, const float* __restrict__ f3,
                      __half* __restrict__ T)
{
    const int t = threadIdx.x;
    int id = blockIdx.x;                           // 0..1663
    const int img = (id >= 832) ? 1 : 0; if (img) id -= 832;
    int lvl, pt;
    if (id < 625)      { lvl = 0; pt = id; }
    else if (id < 782) { lvl = 1; pt = id - 625; }
    else if (id < 822) { lvl = 2; pt = id - 782; }
    else               { lvl = 3; pt = id - 822; }

    const int  Ps[4]   = {40000, 10000, 2500, 625};
    const long TO[4]   = {TOFF0, TOFF1, TOFF2, TOFF3};
    const float* feats[4] = {f0, f1, f2, f3};
    const int P = Ps[lvl];
    const float* __restrict__ src = feats[lvl] + (size_t)img * NCH * (size_t)P;
    __half* __restrict__ dst = T + TO[lvl] + (size_t)img * (size_t)P * NCH;
    const int p0 = pt * 64;

    __shared__ float tile[64][260];   // fp32 staging; stride 260 (1040B, 16B-aligned)

    // ---- phase 1: load 4 p-floats per channel, 8 channels per thread ----
    const int a  = t & 15;            // p4-group
    const int cg = t >> 4;            // 0..31
    const int p4 = a * 4;

#pragma unroll
    for (int i = 0; i < 8; ++i) {
        const int cs = cg + 32 * i;   // 0..255
        const float* sp = src + (size_t)cs * P + p0;
        float4 v;
        if (((P & 3) == 0) && (p0 + p4 + 3 < P)) {
            v = *(const float4*)(sp + p4);       // coalesced 16B, aligned
        } else {
            const int m = P - 1 - p0;            // clamp (edge tile / P=625)
            v.x = sp[min(p4 + 0, m)]; v.y = sp[min(p4 + 1, m)];
            v.z = sp[min(p4 + 2, m)]; v.w = sp[min(p4 + 3, m)];
        }
        tile[p4 + 0][cs] = v.x;
        tile[p4 + 1][cs] = v.y;
        tile[p4 + 2][cs] = v.z;
        tile[p4 + 3][cs] = v.w;
    }
    __syncthreads();

    // ---- phase 2: cvt to fp16, write full [P][C] rows (512B/wave-instr) ----
    const int c4 = (t & 63) * 4;
    const int w  = t >> 6;            // 0..7
#pragma unroll
    for (int i = 0; i < 8; ++i) {
        const int p = w + 8 * i;      // 0..63
        if (p0 + p < P) {
            const __half2 h0 = __floats2half2_rn(tile[p][c4 + 0], tile[p][c4 + 1]);
            const __half2 h1 = __floats2half2_rn(tile[p][c4 + 2], tile[p][c4 + 3]);
            uint2 o;
            o.x = *(const unsigned int*)&h0;
            o.y = *(const unsigned int*)&h1;
            *(uint2*)(dst + (size_t)(p0 + p) * NCH + c4) = o;   // 8B aligned
        }
    }
}

// ---------------- pooler on transposed fp16 layout ----------------
// Block = 1 ROI, 256 threads = 4 waves. Lane owns channels 4l..4l+3 (8B/lane,
// dwordx2): every tap load = 64 lanes x 8B = 512B contiguous, fully coalesced.
// Measured round 7 (fp32 taps): ~42us; fp16 halves tap bytes.
__global__ __launch_bounds__(256)
void pooler_t_kernel(const __half* __restrict__ T,
                     const float* __restrict__ boxes,
                     const int*   __restrict__ img_ids,
                     const int*   __restrict__ order,
                     float* __restrict__ out, int N)
{
    int bx = blockIdx.x;
    int sidx;
    if ((N & 7) == 0) sidx = (bx & 7) * (N >> 3) + (bx >> 3);  // XCD-contiguous
    else              sidx = bx;
    const int roi = order[sidx];
    const int t = threadIdx.x;

    const float bx1 = boxes[roi * 4 + 0];
    const float by1 = boxes[roi * 4 + 1];
    const float bx2 = boxes[roi * 4 + 2];
    const float by2 = boxes[roi * 4 + 3];

    const float area = (bx2 - bx1) * (by2 - by1);
    const float s    = sqrtf(area);
    float lvlf = floorf(4.0f + log2f(s / 224.0f + 1e-6f));
    lvlf = fminf(fmaxf(lvlf, 2.0f), 5.0f);
    const int lvl = (int)lvlf - 2;   // 0..3

    const float scales[4] = {0.25f, 0.125f, 0.0625f, 0.03125f};
    const int   dims[4]   = {200, 100, 50, 25};
    const int   Ps[4]     = {40000, 10000, 2500, 625};
    const long  TO[4]     = {TOFF0, TOFF1, TOFF2, TOFF3};

    const float scale = scales[lvl];
    const int H = dims[lvl];
    const int W = H;
    const int img = img_ids[roi];
    const __half* __restrict__ tb = T + TO[lvl] + (size_t)img * (size_t)Ps[lvl] * NCH;

    const float x1 = bx1 * scale, y1 = by1 * scale;
    const float x2 = bx2 * scale, y2 = by2 * scale;
    const float roi_w = fmaxf(x2 - x1, 1.0f);
    const float roi_h = fmaxf(y2 - y1, 1.0f);
    const float bw = roi_w / (float)OUTD;
    const float bh = roi_h / (float)OUTD;

    __shared__ float4 s_yt[PD];
    __shared__ float4 s_xt[PD];
    __shared__ float  s_out[49 * 260];   // [bin][260]: x4-aligned writes, pad vs 256

    if (t < PD) {
        const int i = t >> 1, j = t & 1;
        const float yg = y1 + (float)i * bh + ((float)j + 0.5f) * bh * 0.5f;
        const float v = ((yg >= -1.0f) && (yg <= (float)H)) ? 1.0f : 0.0f;
        const float y = fminf(fmaxf(yg, 0.0f), (float)(H - 1));
        const int y0 = (int)floorf(y);
        const int y1i = min(y0 + 1, H - 1);
        const float ly = y - (float)y0;
        float4 r;
        r.x = __int_as_float(y0 * W);
        r.y = __int_as_float(y1i * W);
        r.z = (1.0f - ly) * v;
        r.w = ly * v;
        s_yt[t] = r;
    } else if (t < 2 * PD) {
        const int tt = t - PD;
        const int i = tt >> 1, j = tt & 1;
        const float xg = x1 + (float)i * bw + ((float)j + 0.5f) * bw * 0.5f;
        const float v = ((xg >= -1.0f) && (xg <= (float)W)) ? 1.0f : 0.0f;
        const float x = fminf(fmaxf(xg, 0.0f), (float)(W - 1));
        const int x0 = (int)floorf(x);
        const int x1i = min(x0 + 1, W - 1);
        const float lx = x - (float)x0;
        float4 r;
        r.x = __int_as_float(x0);
        r.y = __int_as_float(x1i);
        r.z = (1.0f - lx) * v;
        r.w = lx * v;
        s_xt[tt] = r;
    }
    __syncthreads();

    const int lane = t & 63;
    const int w    = t >> 6;
    const int c4   = lane * 4;

    for (int bin = w; bin < 49; bin += 4) {
        const int ph = (bin * 37) >> 8;        // exact /7 for bin<49
        const int pw = bin - ph * 7;
        float4 acc = {0.0f, 0.0f, 0.0f, 0.0f};
#pragma unroll
        for (int sy = 0; sy < 2; ++sy) {
            const float4 yt = s_yt[ph * 2 + sy];
            const int r0 = __float_as_int(yt.x);
            const int r1 = __float_as_int(yt.y);
            const float hy = yt.z, ly = yt.w;
#pragma unroll
            for (int sx = 0; sx < 2; ++sx) {
                const float4 xt = s_xt[pw * 2 + sx];
                const int xa = __float_as_int(xt.x);
                const int xb = __float_as_int(xt.y);
                const float hx = xt.z, lx = xt.w;
                const float w00 = hy * hx, w01 = hy * lx, w10 = ly * hx, w11 = ly * lx;

                const uint2 q00 = *(const uint2*)(tb + ((size_t)(r0 + xa) << 8) + c4);
                const uint2 q01 = *(const uint2*)(tb + ((size_t)(r0 + xb) << 8) + c4);
                const uint2 q10 = *(const uint2*)(tb + ((size_t)(r1 + xa) << 8) + c4);
                const uint2 q11 = *(const uint2*)(tb + ((size_t)(r1 + xb) << 8) + c4);

                const float2 a0 = __half22float2(*(const __half2*)&q00.x);
                const float2 a1 = __half22float2(*(const __half2*)&q00.y);
                const float2 b0 = __half22float2(*(const __half2*)&q01.x);
                const float2 b1 = __half22float2(*(const __half2*)&q01.y);
                const float2 c0 = __half22float2(*(const __half2*)&q10.x);
                const float2 c1 = __half22float2(*(const __half2*)&q10.y);
                const float2 d0 = __half22float2(*(const __half2*)&q11.x);
                const float2 d1 = __half22float2(*(const __half2*)&q11.y);

                acc.x += w00 * a0.x + w01 * b0.x + w10 * c0.x + w11 * d0.x;
                acc.y += w00 * a0.y + w01 * b0.y + w10 * c0.y + w11 * d0.y;
                acc.z += w00 * a1.x + w01 * b1.x + w10 * c1.x + w11 * d1.x;
                acc.w += w00 * a1.y + w01 * b1.y + w10 * c1.y + w11 * d1.y;
            }
        }
        float4 r;
        r.x = acc.x * 0.25f; r.y = acc.y * 0.25f;
        r.z = acc.z * 0.25f; r.w = acc.w * 0.25f;
        *(float4*)(&s_out[bin * 260 + c4]) = r;
    }
    __syncthreads();

    // coalesced output: 12544 contiguous floats per ROI
    float* __restrict__ outbase = out + (size_t)roi * (NCH * 49);
#pragma unroll
    for (int i = 0; i < 49; ++i) {
        const int e = t + i * 256;
        const int c = (int)(((unsigned)e * 21400u) >> 20);   // exact /49 for e<12544
        const int bin = e - c * 49;
        outbase[e] = s_out[bin * 260 + c];
    }
}

// ---------------- legacy pooler (round-0 verbatim, 101 us): ws-size fallback ----------------
#define LCHUNK 32
__global__ __launch_bounds__(256)
void pooler_legacy(const float* __restrict__ f0,
                   const float* __restrict__ f1,
                   const float* __restrict__ f2,
                   const float* __restrict__ f3,
                   const float* __restrict__ boxes,
                   const int*   __restrict__ img_ids,
                   const int*   __restrict__ order,
                   float* __restrict__ out, int N)
{
    int bx = blockIdx.x;
    int sidx;
    if ((N & 7) == 0) sidx = (bx & 7) * (N >> 3) + (bx >> 3);
    else              sidx = bx;
    const int roi = order[sidx];

    const int c0  = blockIdx.y * LCHUNK;
    const int t   = threadIdx.x;

    const float bx1 = boxes[roi * 4 + 0];
    const float by1 = boxes[roi * 4 + 1];
    const float bx2 = boxes[roi * 4 + 2];
    const float by2 = boxes[roi * 4 + 3];

    const float area = (bx2 - bx1) * (by2 - by1);
    const float s    = sqrtf(area);
    float lvlf = floorf(4.0f + log2f(s / 224.0f + 1e-6f));
    lvlf = fminf(fmaxf(lvlf, 2.0f), 5.0f);
    const int lvl = (int)lvlf - 2;

    const float scales[4] = {0.25f, 0.125f, 0.0625f, 0.03125f};
    const int   dims[4]   = {200, 100, 50, 25};
    const float* feats[4] = {f0, f1, f2, f3};

    const float scale = scales[lvl];
    const int H = dims[lvl];
    const int W = H;
    const int plane = H * W;

    const int img = img_ids[roi];
    const float* __restrict__ base0 =
        feats[lvl] + (size_t)img * NCH * (size_t)plane + (size_t)c0 * plane;

    const float x1 = bx1 * scale, y1 = by1 * scale;
    const float x2 = bx2 * scale, y2 = by2 * scale;
    const float roi_w = fmaxf(x2 - x1, 1.0f);
    const float roi_h = fmaxf(y2 - y1, 1.0f);
    const float bw = roi_w / (float)OUTD;
    const float bh = roi_h / (float)OUTD;

    __shared__ float4 s_yt[PD];
    __shared__ float4 s_xt[PD];
    __shared__ float4 s_xw[OUTD];
    __shared__ int    s_xf[OUTD];
    __shared__ int    s_ok[OUTD];

    if (t < PD) {
        const int i = t >> 1, j = t & 1;
        const float yg = y1 + (float)i * bh + ((float)j + 0.5f) * bh * 0.5f;
        const float v = ((yg >= -1.0f) && (yg <= (float)H)) ? 1.0f : 0.0f;
        const float y = fminf(fmaxf(yg, 0.0f), (float)(H - 1));
        const int y0 = (int)floorf(y);
        const int y1i = min(y0 + 1, H - 1);
        const float ly = y - (float)y0;
        float4 r;
        r.x = __int_as_float(y0 * W);
        r.y = __int_as_float(y1i * W);
        r.z = (1.0f - ly) * v;
        r.w = ly * v;
        s_yt[t] = r;
    } else if (t < 2 * PD) {
        const int tt = t - PD;
        const int i = tt >> 1, j = tt & 1;
        const float xg = x1 + (float)i * bw + ((float)j + 0.5f) * bw * 0.5f;
        const float v = ((xg >= -1.0f) && (xg <= (float)W)) ? 1.0f : 0.0f;
        const float x = fminf(fmaxf(xg, 0.0f), (float)(W - 1));
        const int x0 = (int)floorf(x);
        const float lx = x - (float)x0;
        const float hx = 1.0f - lx;
        const int edge = (x0 == W - 1);
        float4 r;
        r.x = __int_as_float(min(x0, W - 2));
        r.y = edge ? 0.0f   : hx * v;
        r.z = edge ? hx * v : lx * v;
        r.w = 0.0f;
        s_xt[tt] = r;
    } else if (t < 2 * PD + OUTD) {
        const int pw = t - 2 * PD;
        float w[4] = {0.0f, 0.0f, 0.0f, 0.0f};
        int ca[2], cb[2];
        float hxv[2], lxv[2];
#pragma unroll
        for (int j = 0; j < 2; ++j) {
            const float xg = x1 + (float)pw * bw + ((float)j + 0.5f) * bw * 0.5f;
            const float v = ((xg >= -1.0f) && (xg <= (float)W)) ? 1.0f : 0.0f;
            const float x = fminf(fmaxf(xg, 0.0f), (float)(W - 1));
            const int x0 = (int)floorf(x);
            const float lx = x - (float)x0;
            ca[j] = x0;
            cb[j] = min(x0 + 1, W - 1);
            hxv[j] = (1.0f - lx) * v;
            lxv[j] = lx * v;
        }
        const int ok = (cb[1] - ca[0]) <= 3;
        int xf = min(ca[0], W - 4);
        if (xf < 0) xf = 0;
        w[(ca[0] - xf) & 3] += hxv[0];
        w[(cb[0] - xf) & 3] += lxv[0];
        w[(ca[1] - xf) & 3] += hxv[1];
        w[(cb[1] - xf) & 3] += lxv[1];
        float4 wv; wv.x = w[0]; wv.y = w[1]; wv.z = w[2]; wv.w = w[3];
        s_xw[pw] = wv;
        s_xf[pw] = xf;
        s_ok[pw] = ok;
    }
    __syncthreads();

    const bool fused = s_ok[0] && s_ok[1] && s_ok[2] && s_ok[3] &&
                       s_ok[4] && s_ok[5] && s_ok[6];

    float* __restrict__ outbase = out + ((size_t)roi * NCH + c0) * 49;

    if (fused) {
        auto g4 = [&](const float* __restrict__ fp, int ph, int pw, float4* P) {
            const float4 yt0 = s_yt[2 * ph];
            const float4 yt1 = s_yt[2 * ph + 1];
            const int xf = s_xf[pw];
            P[0] = *(const float4*)(fp + __float_as_int(yt0.x) + xf);
            P[1] = *(const float4*)(fp + __float_as_int(yt0.y) + xf);
            P[2] = *(const float4*)(fp + __float_as_int(yt1.x) + xf);
            P[3] = *(const float4*)(fp + __float_as_int(yt1.y) + xf);
        };
        auto r4 = [&](int ph, int pw, const float4* P) -> float {
            const float4 w   = s_xw[pw];
            const float4 yt0 = s_yt[2 * ph];
            const float4 yt1 = s_yt[2 * ph + 1];
            const float d0 = w.x * P[0].x + w.y * P[0].y + w.z * P[0].z + w.w * P[0].w;
            const float d1 = w.x * P[1].x + w.y * P[1].y + w.z * P[1].z + w.w * P[1].w;
            const float d2 = w.x * P[2].x + w.y * P[2].y + w.z * P[2].z + w.w * P[2].w;
            const float d3 = w.x * P[3].x + w.y * P[3].y + w.z * P[3].z + w.w * P[3].w;
            return yt0.z * d0 + yt0.w * d1 + yt1.z * d2 + yt1.w * d3;
        };
        {
            int eA[4], phA[4], pwA[4];
            const float* fpA[4];
#pragma unroll
            for (int j = 0; j < 4; ++j) {
                const int e = t + j * 256;
                const int c = e / 49, bin = e - c * 49;
                phA[j] = bin / 7;
                pwA[j] = bin - phA[j] * 7;
                eA[j]  = e;
                fpA[j] = base0 + (size_t)c * plane;
            }
            float4 P[4][4];
#pragma unroll
            for (int j = 0; j < 4; ++j) g4(fpA[j], phA[j], pwA[j], P[j]);
            __builtin_amdgcn_sched_barrier(0);
#pragma unroll
            for (int j = 0; j < 4; ++j)
                outbase[eA[j]] = r4(phA[j], pwA[j], P[j]) * 0.25f;
        }
        {
            int eA[2], phA[2], pwA[2];
            const float* fpA[2];
#pragma unroll
            for (int j = 0; j < 2; ++j) {
                const int e = t + (4 + j) * 256;
                const int c = e / 49, bin = e - c * 49;
                phA[j] = bin / 7;
                pwA[j] = bin - phA[j] * 7;
                eA[j]  = e;
                fpA[j] = base0 + (size_t)c * plane;
            }
            float4 P[2][4];
#pragma unroll
            for (int j = 0; j < 2; ++j) g4(fpA[j], phA[j], pwA[j], P[j]);
            __builtin_amdgcn_sched_barrier(0);
#pragma unroll
            for (int j = 0; j < 2; ++j)
                outbase[eA[j]] = r4(phA[j], pwA[j], P[j]) * 0.25f;
        }
        if (t < 32) {
            const int e = 1536 + t;
            const int c = e / 49, bin = e - c * 49;
            const int ph = bin / 7, pw = bin - ph * 7;
            const float* fp = base0 + (size_t)c * plane;
            float4 P[4];
            g4(fp, ph, pw, P);
            outbase[e] = r4(ph, pw, P) * 0.25f;
        }
    } else {
        auto gather = [&](const float* __restrict__ fp, int ph, int pw, float2* P) {
#pragma unroll
            for (int sy = 0; sy < 2; ++sy) {
                const float4 yt = s_yt[ph * 2 + sy];
                const int ro0 = __float_as_int(yt.x);
                const int ro1 = __float_as_int(yt.y);
#pragma unroll
                for (int sx = 0; sx < 2; ++sx) {
                    const float4 xt = s_xt[pw * 2 + sx];
                    const int xa = __float_as_int(xt.x);
                    P[(sy * 2 + sx) * 2 + 0] = *(const float2*)(fp + ro0 + xa);
                    P[(sy * 2 + sx) * 2 + 1] = *(const float2*)(fp + ro1 + xa);
                }
            }
        };
        auto reduce = [&](int ph, int pw, const float2* P) -> float {
            float acc = 0.0f;
#pragma unroll
            for (int sy = 0; sy < 2; ++sy) {
                const float4 yt = s_yt[ph * 2 + sy];
                const float hy = yt.z, ly = yt.w;
#pragma unroll
                for (int sx = 0; sx < 2; ++sx) {
                    const float4 xt = s_xt[pw * 2 + sx];
                    const float wlo = xt.y, whi = xt.z;
                    const float2 p0 = P[(sy * 2 + sx) * 2 + 0];
                    const float2 p1 = P[(sy * 2 + sx) * 2 + 1];
                    acc += hy * (wlo * p0.x + whi * p0.y)
                         + ly * (wlo * p1.x + whi * p1.y);
                }
            }
            return acc;
        };
#pragma unroll
        for (int kk = 0; kk < 2; ++kk) {
            int eA[3], phA[3], pwA[3];
            const float* fpA[3];
#pragma unroll
            for (int j = 0; j < 3; ++j) {
                const int e = t + (kk * 3 + j) * 256;
                const int c = e / 49, bin = e - c * 49;
                phA[j] = bin / 7;
                pwA[j] = bin - phA[j] * 7;
                eA[j]  = e;
                fpA[j] = base0 + (size_t)c * plane;
            }
            float2 P[3][8];
#pragma unroll
            for (int j = 0; j < 3; ++j) gather(fpA[j], phA[j], pwA[j], P[j]);
            __builtin_amdgcn_sched_barrier(0);
#pragma unroll
            for (int j = 0; j < 3; ++j)
                outbase[eA[j]] = reduce(phA[j], pwA[j], P[j]) * 0.25f;
        }
        if (t < 32) {
            const int e = 1536 + t;
            const int c = e / 49, bin = e - c * 49;
            const int ph = bin / 7, pw = bin - ph * 7;
            const float* fp = base0 + (size_t)c * plane;
            float2 P[8];
            gather(fp, ph, pw, P);
            outbase[e] = reduce(ph, pw, P) * 0.25f;
        }
    }
}

extern "C" void kernel_launch(void* const* d_in, const int* in_sizes, int n_in,
                              void* d_out, int out_size, void* d_ws, size_t ws_size,
                              hipStream_t stream) {
    const float* f0    = (const float*)d_in[0];
    const float* f1    = (const float*)d_in[1];
    const float* f2    = (const float*)d_in[2];
    const float* f3    = (const float*)d_in[3];
    const float* boxes = (const float*)d_in[4];
    const int*   ids   = (const int*)d_in[5];
    float* out = (float*)d_out;
    int*   order = (int*)d_ws;

    const int N = in_sizes[4] / 4;   // number of ROIs (1000)

    const size_t need = (size_t)TBASE_BYTES + (size_t)TTOT * sizeof(__half);

    sort_kernel<<<1, 1024, 0, stream>>>(boxes, ids, order, N);

    if (ws_size >= need) {
        __half* T = (__half*)((char*)d_ws + TBASE_BYTES);
        transpose_kernel<<<1664, 512, 0, stream>>>(f0, f1, f2, f3, T);
        pooler_t_kernel<<<N, 256, 0, stream>>>(T, boxes, ids, order, out, N);
    } else {
        dim3 grid(N, NCH / LCHUNK);
        pooler_legacy<<<grid, 256, 0, stream>>>(f0, f1, f2, f3, boxes, ids, order, out, N);
    }
}